// Round 2
// baseline (898.812 us; speedup 1.0000x reference)
//
#include <hip/hip_runtime.h>
#include <hip/hip_bf16.h>

// Hyperbolic linear (Poincare ball, c=1):
//   mx = x @ W^T (bf16 MFMA, fp32 accum)
//   everything downstream is out = a*mx + g*hb with per-row scalars a,g
//   derived from xn2=|x|^2, m2=|mx|^2, d=mx.hb (hb = proj(expmap0(bias))).
// Memory-bound: 1.07 GB traffic -> ~170us floor at 6.3 TB/s.

typedef __bf16 bf16x8 __attribute__((ext_vector_type(8)));
typedef float  f32x4  __attribute__((ext_vector_type(4)));

#define MAXN 0.99999f   // (1 - BALL_EPS)/sqrt(c)
#define EPSN 1e-15f     // norm clamp

__global__ __launch_bounds__(256)
void hyp_lin_kernel(const float* __restrict__ X, const float* __restrict__ W,
                    const float* __restrict__ Bv, float* __restrict__ O, int nrows)
{
    const int lane = threadIdx.x & 63;
    const int lg = lane >> 4;   // k-group 0..3
    const int lm = lane & 15;   // row (A) / col (B,C) within 16-tile
    const int gwave = blockIdx.x * 4 + (threadIdx.x >> 6);
    const int nwaves = gridDim.x * 4;

    // ---- one-time: W -> B fragments (B[k][n] = W[n][k]); lane: n=lm, k=lg*8+i (+32c)
    bf16x8 bfrag[4][2];
#pragma unroll
    for (int t = 0; t < 4; ++t) {
        const float* wrow = W + (t * 16 + lm) * 64;
#pragma unroll
        for (int c = 0; c < 2; ++c) {
            const float4 w0 = *reinterpret_cast<const float4*>(wrow + c * 32 + lg * 8);
            const float4 w1 = *reinterpret_cast<const float4*>(wrow + c * 32 + lg * 8 + 4);
            bf16x8 f;
            f[0] = (__bf16)w0.x; f[1] = (__bf16)w0.y; f[2] = (__bf16)w0.z; f[3] = (__bf16)w0.w;
            f[4] = (__bf16)w1.x; f[5] = (__bf16)w1.y; f[6] = (__bf16)w1.z; f[7] = (__bf16)w1.w;
            bfrag[t][c] = f;
        }
    }

    // ---- one-time: hyp_bias = proj(expmap0(bias)); lane holds cols lm+16t
    float braw[4];
    float bn2 = 0.f;
#pragma unroll
    for (int t = 0; t < 4; ++t) { braw[t] = Bv[t * 16 + lm]; bn2 += braw[t] * braw[t]; }
#pragma unroll
    for (int m = 1; m <= 8; m <<= 1) bn2 += __shfl_xor(bn2, m);   // sum all 64 cols
    const float bn = fmaxf(sqrtf(bn2), EPSN);
    const float tb = tanhf(bn);
    float bscale = tb / bn;                       // expmap0 scale
    if (fabsf(tb) > MAXN) bscale *= MAXN / fabsf(tb);   // proj (no-op for this data)
    float hb[4];
#pragma unroll
    for (int t = 0; t < 4; ++t) hb[t] = braw[t] * bscale;
    const float y2 = bscale * bscale * bn2;       // |hb|^2

    const int ntiles = (nrows + 15) >> 4;
    for (int tile = gwave; tile < ntiles; tile += nwaves) {
        const int rb = tile << 4;
        int lrow = rb + lm; if (lrow > nrows - 1) lrow = nrows - 1;
        const float* xp = X + (size_t)lrow * 64 + lg * 8;
        const float4 x0 = *reinterpret_cast<const float4*>(xp);
        const float4 x1 = *reinterpret_cast<const float4*>(xp + 4);
        const float4 x2 = *reinterpret_cast<const float4*>(xp + 32);
        const float4 x3 = *reinterpret_cast<const float4*>(xp + 36);

        // |x|^2 per row (row index = lm in this layout)
        float xs = x0.x*x0.x + x0.y*x0.y + x0.z*x0.z + x0.w*x0.w
                 + x1.x*x1.x + x1.y*x1.y + x1.z*x1.z + x1.w*x1.w
                 + x2.x*x2.x + x2.y*x2.y + x2.z*x2.z + x2.w*x2.w
                 + x3.x*x3.x + x3.y*x3.y + x3.z*x3.z + x3.w*x3.w;
        xs += __shfl_xor(xs, 16);
        xs += __shfl_xor(xs, 32);   // now full |x[lm]|^2 on every lane

        // x -> A fragments (row=lm, k=lg*8+i, +32 for chunk 1)
        bf16x8 a0, a1;
        a0[0]=(__bf16)x0.x; a0[1]=(__bf16)x0.y; a0[2]=(__bf16)x0.z; a0[3]=(__bf16)x0.w;
        a0[4]=(__bf16)x1.x; a0[5]=(__bf16)x1.y; a0[6]=(__bf16)x1.z; a0[7]=(__bf16)x1.w;
        a1[0]=(__bf16)x2.x; a1[1]=(__bf16)x2.y; a1[2]=(__bf16)x2.z; a1[3]=(__bf16)x2.w;
        a1[4]=(__bf16)x3.x; a1[5]=(__bf16)x3.y; a1[6]=(__bf16)x3.z; a1[7]=(__bf16)x3.w;

        f32x4 acc[4];
#pragma unroll
        for (int t = 0; t < 4; ++t) {
            f32x4 z = {0.f, 0.f, 0.f, 0.f};
            z = __builtin_amdgcn_mfma_f32_16x16x32_bf16(a0, bfrag[t][0], z, 0, 0, 0);
            z = __builtin_amdgcn_mfma_f32_16x16x32_bf16(a1, bfrag[t][1], z, 0, 0, 0);
            acc[t] = z;
        }

        // per-row |mx|^2 and mx.hb ; C layout: col=lm, row=4*lg+reg
        float m2[4] = {0,0,0,0}, dd[4] = {0,0,0,0};
#pragma unroll
        for (int t = 0; t < 4; ++t)
#pragma unroll
            for (int r = 0; r < 4; ++r) {
                const float v = acc[t][r];
                m2[r] += v * v;
                dd[r] += v * hb[t];
            }
#pragma unroll
        for (int r = 0; r < 4; ++r)
#pragma unroll
            for (int m = 1; m <= 8; m <<= 1) {
                m2[r] += __shfl_xor(m2[r], m);
                dd[r] += __shfl_xor(dd[r], m);
            }

        // per-row scalar chain (4 rows per lane-group, reg-indexed)
        float aa[4], gg[4];
#pragma unroll
        for (int r = 0; r < 4; ++r) {
            const float xn2 = __shfl(xs, 4 * lg + r);       // |x|^2 of row 4*lg+r
            const float xn  = fmaxf(sqrtf(xn2), EPSN);
            const float mxn = fmaxf(sqrtf(m2[r]), EPSN);
            const float xc  = fminf(xn, 1.f - 1e-7f);
            const float at  = 0.5f * log1pf(2.f * xc / (1.f - xc));   // artanh
            const float th  = tanhf((mxn / xn) * at);
            float s = th / mxn;                              // res = s * mx
            if (th > MAXN) s *= MAXN / th;                   // proj(mv): |mv| = th
            const float x2v = s * s * m2[r];                 // |res|^2
            const float xy  = s * dd[r];                     // res.hb
            const float A_  = 1.f + 2.f * xy + y2;
            const float B_  = 1.f - x2v;
            float den = 1.f + 2.f * xy + x2v * y2;
            den = fmaxf(den, EPSN);
            float a_ = A_ * s / den;
            float g_ = B_ / den;
            const float nn2 = a_ * a_ * m2[r] + 2.f * a_ * g_ * dd[r] + g_ * g_ * y2;
            const float nn  = sqrtf(nn2);                    // |out| (analytic)
            if (nn > MAXN) { const float sc = MAXN / nn; a_ *= sc; g_ *= sc; }
            aa[r] = a_; gg[r] = g_;
        }

        // out = a*mx + g*hb ; store (row = rb+4*lg+r, col = 16t+lm)
#pragma unroll
        for (int r = 0; r < 4; ++r) {
            const int orow = rb + 4 * lg + r;
            if (orow < nrows) {
                float* op = O + (size_t)orow * 64 + lm;
#pragma unroll
                for (int t = 0; t < 4; ++t)
                    op[t * 16] = aa[r] * acc[t][r] + gg[r] * hb[t];
            }
        }
    }
}

extern "C" void kernel_launch(void* const* d_in, const int* in_sizes, int n_in,
                              void* d_out, int out_size, void* d_ws, size_t ws_size,
                              hipStream_t stream)
{
    const float* X = (const float*)d_in[0];
    const float* W = (const float*)d_in[1];
    const float* B = (const float*)d_in[2];
    float* O = (float*)d_out;
    const int nrows = in_sizes[0] / 64;
    hipLaunchKernelGGL(hyp_lin_kernel, dim3(2048), dim3(256), 0, stream, X, W, B, O, nrows);
}

// Round 3
// 854.410 us; speedup vs baseline: 1.0520x; 1.0520x over previous
//
#include <hip/hip_runtime.h>
#include <hip/hip_bf16.h>

// Hyperbolic linear (Poincare ball, c=1), transposed-MFMA variant:
//   D = W @ x^T  (A = W rows, B = x^T)  ->  lane (lm,lg) holds 16 components
//   of output row lm at out-dims 16t+4lg+{0..3}: contiguous float4 chunks.
//   out = a*mx + g*hb with per-row scalars from xn2=|x|^2, m2=|mx|^2, d=mx.hb.
// Memory-bound: 1.07 GB traffic -> ~170us floor at 6.3 TB/s.

typedef __bf16 bf16x8 __attribute__((ext_vector_type(8)));
typedef float  f32x4  __attribute__((ext_vector_type(4)));

#define MAXN 0.99999f   // (1 - BALL_EPS)/sqrt(c)
#define EPSN 1e-15f     // norm clamp

__global__ __launch_bounds__(256)
void hyp_lin_kernel(const float* __restrict__ X, const float* __restrict__ W,
                    const float* __restrict__ Bv, float* __restrict__ O, int nrows)
{
    const int lane = threadIdx.x & 63;
    const int lg = lane >> 4;   // lane group 0..3
    const int lm = lane & 15;   // A row (out-dim) / B col (x-row) within 16-tile
    const int gwave = blockIdx.x * 4 + (threadIdx.x >> 6);
    const int nwaves = gridDim.x * 4;

    // ---- one-time: W -> A fragments; wfrag[t][c][i] = W[16t+lm][c*32+lg*8+i]
    bf16x8 wfrag[4][2];
#pragma unroll
    for (int t = 0; t < 4; ++t) {
        const float* wrow = W + (t * 16 + lm) * 64;
#pragma unroll
        for (int c = 0; c < 2; ++c) {
            const float4 w0 = *reinterpret_cast<const float4*>(wrow + c * 32 + lg * 8);
            const float4 w1 = *reinterpret_cast<const float4*>(wrow + c * 32 + lg * 8 + 4);
            bf16x8 f;
            f[0] = (__bf16)w0.x; f[1] = (__bf16)w0.y; f[2] = (__bf16)w0.z; f[3] = (__bf16)w0.w;
            f[4] = (__bf16)w1.x; f[5] = (__bf16)w1.y; f[6] = (__bf16)w1.z; f[7] = (__bf16)w1.w;
            wfrag[t][c] = f;
        }
    }

    // ---- one-time: hyp_bias = proj(expmap0(bias)); lane needs dims 16t+4lg+r
    float hb[4][4];
    float bn2 = 0.f;
#pragma unroll
    for (int t = 0; t < 4; ++t)
#pragma unroll
        for (int r = 0; r < 4; ++r) {
            const float b = Bv[t * 16 + lg * 4 + r];
            hb[t][r] = b;
            bn2 += b * b;
        }
    bn2 += __shfl_xor(bn2, 16);
    bn2 += __shfl_xor(bn2, 32);          // lanes differing in lg hold disjoint dims
    const float bn = fmaxf(sqrtf(bn2), EPSN);
    const float tb = tanhf(bn);
    float bscale = tb / bn;                            // expmap0 scale
    if (fabsf(tb) > MAXN) bscale *= MAXN / fabsf(tb);  // proj (no-op for this data)
#pragma unroll
    for (int t = 0; t < 4; ++t)
#pragma unroll
        for (int r = 0; r < 4; ++r) hb[t][r] *= bscale;
    const float y2 = bscale * bscale * bn2;            // |hb|^2

    const int ntiles = (nrows + 15) >> 4;
    for (int tile = gwave; tile < ntiles; tile += nwaves) {
        const int rb = tile << 4;
        int lrow = rb + lm; if (lrow > nrows - 1) lrow = nrows - 1;
        const float* xp = X + (size_t)lrow * 64 + lg * 8;
        const float4 x0 = *reinterpret_cast<const float4*>(xp);
        const float4 x1 = *reinterpret_cast<const float4*>(xp + 4);
        const float4 x2 = *reinterpret_cast<const float4*>(xp + 32);
        const float4 x3 = *reinterpret_cast<const float4*>(xp + 36);

        // |x|^2 of row lm: in-lane partial + reduce over lg groups
        float xs = x0.x*x0.x + x0.y*x0.y + x0.z*x0.z + x0.w*x0.w
                 + x1.x*x1.x + x1.y*x1.y + x1.z*x1.z + x1.w*x1.w
                 + x2.x*x2.x + x2.y*x2.y + x2.z*x2.z + x2.w*x2.w
                 + x3.x*x3.x + x3.y*x3.y + x3.z*x3.z + x3.w*x3.w;
        xs += __shfl_xor(xs, 16);
        xs += __shfl_xor(xs, 32);        // full |x[lm]|^2 on every lane

        // x -> B fragments (col=lm=x-row, k=lg*8+i; chunk 1 at k+32)
        bf16x8 b0, b1;
        b0[0]=(__bf16)x0.x; b0[1]=(__bf16)x0.y; b0[2]=(__bf16)x0.z; b0[3]=(__bf16)x0.w;
        b0[4]=(__bf16)x1.x; b0[5]=(__bf16)x1.y; b0[6]=(__bf16)x1.z; b0[7]=(__bf16)x1.w;
        b1[0]=(__bf16)x2.x; b1[1]=(__bf16)x2.y; b1[2]=(__bf16)x2.z; b1[3]=(__bf16)x2.w;
        b1[4]=(__bf16)x3.x; b1[5]=(__bf16)x3.y; b1[6]=(__bf16)x3.z; b1[7]=(__bf16)x3.w;

        // D[out][row]: acc[t][r] = mx[row=lm][out=16t+4lg+r]
        f32x4 acc[4];
#pragma unroll
        for (int t = 0; t < 4; ++t) {
            f32x4 z = {0.f, 0.f, 0.f, 0.f};
            z = __builtin_amdgcn_mfma_f32_16x16x32_bf16(wfrag[t][0], b0, z, 0, 0, 0);
            z = __builtin_amdgcn_mfma_f32_16x16x32_bf16(wfrag[t][1], b1, z, 0, 0, 0);
            acc[t] = z;
        }

        // |mx|^2 and mx.hb for row lm: in-lane (16 dims) + reduce over lg groups
        float m2 = 0.f, dd = 0.f;
#pragma unroll
        for (int t = 0; t < 4; ++t)
#pragma unroll
            for (int r = 0; r < 4; ++r) {
                const float v = acc[t][r];
                m2 += v * v;
                dd += v * hb[t][r];
            }
        m2 += __shfl_xor(m2, 16);  m2 += __shfl_xor(m2, 32);
        dd += __shfl_xor(dd, 16);  dd += __shfl_xor(dd, 32);

        // per-row scalar chain (ONE per lane; row = lm)
        const float xn  = fmaxf(sqrtf(xs), EPSN);
        const float mxn = fmaxf(sqrtf(m2), EPSN);
        const float xc  = fminf(xn, 1.f - 1e-7f);
        const float at  = 0.5f * log1pf(2.f * xc / (1.f - xc));   // artanh
        const float th  = tanhf((mxn / xn) * at);
        float s = th / mxn;                              // res = s * mx
        if (th > MAXN) s *= MAXN / th;                   // proj(mv): |mv| = th
        const float x2v = s * s * m2;                    // |res|^2
        const float xy  = s * dd;                        // res.hb
        const float A_  = 1.f + 2.f * xy + y2;
        const float B_  = 1.f - x2v;
        float den = 1.f + 2.f * xy + x2v * y2;
        den = fmaxf(den, EPSN);
        float a_ = A_ * s / den;
        float g_ = B_ / den;
        const float nn2 = a_ * a_ * m2 + 2.f * a_ * g_ * dd + g_ * g_ * y2;
        const float nn  = sqrtf(nn2);                    // |out| (analytic)
        if (nn > MAXN) { const float sc = MAXN / nn; a_ *= sc; g_ *= sc; }

        // out = a*mx + g*hb ; 4x float4 stores: row rb+lm, cols 16t+4lg+{0..3}
        if (rb + lm < nrows) {
            float* op = O + (size_t)(rb + lm) * 64 + lg * 4;
#pragma unroll
            for (int t = 0; t < 4; ++t) {
                float4 o;
                o.x = a_ * acc[t][0] + g_ * hb[t][0];
                o.y = a_ * acc[t][1] + g_ * hb[t][1];
                o.z = a_ * acc[t][2] + g_ * hb[t][2];
                o.w = a_ * acc[t][3] + g_ * hb[t][3];
                *reinterpret_cast<float4*>(op + t * 16) = o;
            }
        }
    }
}

extern "C" void kernel_launch(void* const* d_in, const int* in_sizes, int n_in,
                              void* d_out, int out_size, void* d_ws, size_t ws_size,
                              hipStream_t stream)
{
    const float* X = (const float*)d_in[0];
    const float* W = (const float*)d_in[1];
    const float* B = (const float*)d_in[2];
    float* O = (float*)d_out;
    const int nrows = in_sizes[0] / 64;
    hipLaunchKernelGGL(hyp_lin_kernel, dim3(2048), dim3(256), 0, stream, X, W, B, O, nrows);
}